// Round 4
// baseline (101.270 us; speedup 1.0000x reference)
//
#include <hip/hip_runtime.h>
#include <hip/hip_bf16.h>

// Chamfer loss: pred [8,4096,3] f32, gt [8,4096,3] f32 -> scalar f32.
// loss = mean_b[ mean(d1)+mean(d2) + 3*(mean(top2048(d1)) + mean(top2048(d2))) ]
// d1[n] = sqrt(min_m ||p_n - g_m||^2), d2 symmetric.
//
// Fixed floor (round-2/3 profile): harness re-poisons the full 256 MB d_ws
// before every timed launch (~40 us fillBuffer @ 6.7 TB/s) — untouchable.
//
// Round-4 structure: no atomics. Each (qc,dc) block writes its partial min
// with plain coalesced stores; select_kernel folds the 32-way reduction.
// Inner loop is 4 VALU/pair: min_m(qn+gn-2dot) = qn + min_m(gn-2dot), with
// db packed as (-2x,-2y,-2z,|g|^2); qn added once in the epilogue.

#define BATCH 8
#define NPTS  4096
#define TOPK  2048
#define TQ    8      // queries per thread (amortize each LDS read over 8 pairs)
#define BT    256    // threads per block
#define QCHUNK (BT * TQ)   // 2048 queries per block
#define DCHUNK 128         // db points per block chunk
#define NDC   (NPTS / DCHUNK)  // 32 db chunks
#define NROW  (2 * BATCH)      // 16 rows = b*2+dir

// ---------------- Kernel A: partial min over one db chunk ------------------
// grid (2,32,16) = 1024 blocks -> 4 blocks/CU, 4 waves/SIMD.
// Per db point per wave: 1 broadcast ds_read_b128 + 32 VALU (8q x {3 fma, min}).
__global__ __launch_bounds__(BT) void nn_min_kernel(
    const float* __restrict__ pred, const float* __restrict__ gt,
    float* __restrict__ partials /* [NDC*NROW][NPTS] */) {
  const int qc  = blockIdx.x;          // 0..1 query chunk
  const int dc  = blockIdx.y;          // 0..31 db chunk
  const int bz  = blockIdx.z;          // b*2 + dir
  const int b   = bz >> 1;
  const int dir = bz & 1;
  const float* q = (dir == 0 ? pred : gt) + (size_t)b * NPTS * 3;
  const float* g = (dir == 0 ? gt : pred) + (size_t)b * NPTS * 3;

  __shared__ float4 db[DCHUNK];
  const int tid = threadIdx.x;

  if (tid < DCHUNK) {
    int gi = dc * DCHUNK + tid;        // one point per thread
    float x = g[3 * gi + 0];
    float y = g[3 * gi + 1];
    float z = g[3 * gi + 2];
    db[tid] = make_float4(-2.0f * x, -2.0f * y, -2.0f * z,
                          x * x + y * y + z * z);
  }

  // load this thread's queries
  float qx[TQ], qy[TQ], qz[TQ], qn[TQ], m[TQ];
#pragma unroll
  for (int j = 0; j < TQ; j++) {
    int qi = qc * QCHUNK + tid + BT * j;
    qx[j] = q[3 * qi + 0];
    qy[j] = q[3 * qi + 1];
    qz[j] = q[3 * qi + 2];
    qn[j] = qx[j] * qx[j] + qy[j] * qy[j] + qz[j] * qz[j];
    m[j]  = 3.0e38f;
  }
  __syncthreads();

#pragma unroll 4
  for (int i = 0; i < DCHUNK; i++) {
    float4 gp = db[i];   // uniform address -> broadcast, no bank conflicts
#pragma unroll
    for (int j = 0; j < TQ; j++) {
      float t = fmaf(gp.x, qx[j], gp.w);   // gn - 2*dot (qn folded out)
      t = fmaf(gp.y, qy[j], t);
      t = fmaf(gp.z, qz[j], t);
      m[j] = fminf(m[j], t);
    }
  }

  // plain coalesced partial-min stores (no atomics, no sentinel memset)
  float* outrow = partials + ((size_t)dc * NROW + bz) * NPTS + qc * QCHUNK;
#pragma unroll
  for (int j = 0; j < TQ; j++) {
    outrow[tid + BT * j] = fmaxf(qn[j] + m[j], 0.0f);
  }
}

// ---------------- Kernel B: 32-way min-reduce + sqrt + mean + exact top-k,
// then atomicAdd into out (out zeroed by 4B memset in kernel_launch) --------
__global__ __launch_bounds__(BT) void select_kernel(
    const float* __restrict__ partials, float* __restrict__ out) {
  const int row = blockIdx.x;                // 0..15 = b*2+dir
  const int tid = threadIdx.x;

  __shared__ float sf[4];
  __shared__ int   si[4];

  const int PER = NPTS / BT;  // 16 queries per thread
  float sq[PER];
#pragma unroll
  for (int j = 0; j < PER; j++) sq[j] = 3.0e38f;

  // fold 32 partial-min copies; each pass is a fully-coalesced row read
#pragma unroll 4
  for (int p = 0; p < NDC; p++) {
    const float* src = partials + ((size_t)p * NROW + row) * NPTS;
#pragma unroll
    for (int j = 0; j < PER; j++)
      sq[j] = fminf(sq[j], src[tid + BT * j]);
  }

  float d[PER];
  float sum_all = 0.0f;
#pragma unroll
  for (int j = 0; j < PER; j++) {
    float v = sqrtf(sq[j]);
    d[j] = v;
    sum_all += v;
  }

  // block float sum of sum_all
  {
    float v = sum_all;
    for (int off = 32; off > 0; off >>= 1) v += __shfl_down(v, off);
    if ((tid & 63) == 0) sf[tid >> 6] = v;
    __syncthreads();
    sum_all = sf[0] + sf[1] + sf[2] + sf[3];
    __syncthreads();
  }

  // radix-select the TOPK-th largest value (exact, over float bit patterns)
  unsigned sel = 0u;
  for (int bit = 30; bit >= 0; --bit) {   // sign bit is 0 (nonneg)
    unsigned cand = sel | (1u << bit);
    int c = 0;
#pragma unroll
    for (int j = 0; j < PER; j++) c += (__float_as_uint(d[j]) >= cand) ? 1 : 0;
    for (int off = 32; off > 0; off >>= 1) c += __shfl_down(c, off);
    if ((tid & 63) == 0) si[tid >> 6] = c;
    __syncthreads();
    int total = si[0] + si[1] + si[2] + si[3];
    __syncthreads();
    if (total >= TOPK) sel = cand;
  }

  // sum of strictly-greater values + count
  int cgt = 0;
  float sgt = 0.0f;
#pragma unroll
  for (int j = 0; j < PER; j++) {
    if (__float_as_uint(d[j]) > sel) { cgt++; sgt += d[j]; }
  }
  {
    float v = sgt;
    for (int off = 32; off > 0; off >>= 1) v += __shfl_down(v, off);
    if ((tid & 63) == 0) sf[tid >> 6] = v;
    int c = cgt;
    for (int off = 32; off > 0; off >>= 1) c += __shfl_down(c, off);
    if ((tid & 63) == 0) si[tid >> 6] = c;
    __syncthreads();
    sgt = sf[0] + sf[1] + sf[2] + sf[3];
    cgt = si[0] + si[1] + si[2] + si[3];
  }

  if (tid == 0) {
    float kth = __uint_as_float(sel);
    float topk_sum = sgt + (float)(TOPK - cgt) * kth;  // tie-exact vs lax.top_k
    float rowval = sum_all / (float)NPTS + 3.0f * (topk_sum / (float)TOPK);
    atomicAdd(out, rowval * (1.0f / (float)BATCH));
  }
}

extern "C" void kernel_launch(void* const* d_in, const int* in_sizes, int n_in,
                              void* d_out, int out_size, void* d_ws, size_t ws_size,
                              hipStream_t stream) {
  const float* pred = (const float*)d_in[0];
  const float* gt   = (const float*)d_in[1];
  float* out = (float*)d_out;

  float* partials = (float*)d_ws;   // [NDC*NROW][NPTS] = 8 MB

  hipMemsetAsync(d_out, 0, sizeof(float), stream);

  dim3 gridA(NPTS / QCHUNK, NDC, NROW);  // (2,32,16) = 1024 blocks
  nn_min_kernel<<<gridA, BT, 0, stream>>>(pred, gt, partials);
  select_kernel<<<NROW, BT, 0, stream>>>(partials, out);
}

// Round 5
// 92.588 us; speedup vs baseline: 1.0938x; 1.0938x over previous
//
#include <hip/hip_runtime.h>
#include <hip/hip_bf16.h>

// Chamfer loss: pred [8,4096,3] f32, gt [8,4096,3] f32 -> scalar f32.
// loss = mean_b[ mean(d1)+mean(d2) + 3*(mean(top2048(d1)) + mean(top2048(d2))) ]
// d1[n] = sqrt(min_m ||p_n - g_m||^2), d2 symmetric.
//
// Fixed floor (round-2/3/4 profile): harness re-poisons the full 256 MB d_ws
// before every timed launch (~41 us fillBuffer @ 6.7 TB/s) — untouchable.
//
// Round-5: scalar-VALU distance loop was stuck at ~36 us across 3 variants
// (R2/R3/R4 all ~98-101 us total) — VALU-issue-bound ~2.5x above the naive
// 2cyc/inst model. Move the dot products to the MFMA pipe:
//   sqd[q][g] = qn_fp32 + (A.B)  with A=(qx,qy,qz,1) f16, B=(-2gx,-2gy,-2gz,gn) f16
// One mfma_f32_16x16x32_f16 covers 16q x 16g = 256 pairs (K=4 of 32 used).
// f16 rounding perturbs points by ~1e-3 -> final scalar err ~1e-3 << 3.3e-2.
// Each wave: 16 queries x all 4096 g -> running fmin in 4 C-regs, one 16-lane
// shuffle-min epilogue, direct store of final minsq (no partials, no atomics).

#define BATCH 8
#define NPTS  4096
#define TOPK  2048
#define BT    256
#define NROW  (2 * BATCH)      // 16 rows = b*2+dir
#define NTILE (NPTS / 16)      // 256 g-tiles per wave

typedef _Float16 half8 __attribute__((ext_vector_type(8)));
typedef float floatx4 __attribute__((ext_vector_type(4)));

static __device__ inline unsigned pack_h2(float a, float b) {
  unsigned short ua = __builtin_bit_cast(unsigned short, (_Float16)a);
  unsigned short ub = __builtin_bit_cast(unsigned short, (_Float16)b);
  return (unsigned)ua | ((unsigned)ub << 16);
}

// ---------------- Kernel A: min squared distance via MFMA ------------------
// grid (64,16) = 1024 blocks -> 4 blocks/CU, 16 waves/CU, 4 waves/SIMD.
// Per wave per g-tile: 1 ds_read_b64 (quad0 lanes; others broadcast a zero
// slot) + 1 addr add + 1 MFMA + 4 v_min.
__global__ __launch_bounds__(BT) void nn_min_kernel(
    const float* __restrict__ pred, const float* __restrict__ gt,
    float* __restrict__ minsq /* [NROW][NPTS] */, float* __restrict__ out) {
  const int qb  = blockIdx.x;          // 0..63: query block of 64
  const int bz  = blockIdx.y;          // b*2 + dir
  const int b   = bz >> 1;
  const int dir = bz & 1;
  const float* q = (dir == 0 ? pred : gt) + (size_t)b * NPTS * 3;
  const float* g = (dir == 0 ? gt : pred) + (size_t)b * NPTS * 3;

  // db staged as f16x4 (-2x,-2y,-2z,|g|^2) packed in uint2; gsh[NPTS] = zeros
  // (broadcast target for lanes outside quad 0).
  __shared__ uint2 gsh[NPTS + 8];
  const int tid = threadIdx.x;

#pragma unroll
  for (int s = 0; s < NPTS / BT; s++) {
    int gi = tid + BT * s;
    float x = g[3 * gi + 0];
    float y = g[3 * gi + 1];
    float z = g[3 * gi + 2];
    float gn = x * x + y * y + z * z;
    gsh[gi] = make_uint2(pack_h2(-2.0f * x, -2.0f * y), pack_h2(-2.0f * z, gn));
  }
  if (tid == 0) gsh[NPTS] = make_uint2(0u, 0u);
  if (tid == 0 && qb == 0 && bz == 0) out[0] = 0.0f;  // select accumulates here

  const int lane = tid & 63;
  const int wave = tid >> 6;
  const int quad = lane >> 4;   // k-group: quad*8 + j
  const int col  = lane & 15;
  const int q0   = qb * 64 + wave * 16;   // this wave's 16 queries

  // A fragment: lane(quad0,col) holds A[m=col][k=0..7] = (qx,qy,qz,1,0,0,0,0);
  // all other lanes zero (k>=8 rows of A are zero).
  half8 afrag = {};
  if (quad == 0) {
    int qi = q0 + col;
    afrag[0] = (_Float16)q[3 * qi + 0];
    afrag[1] = (_Float16)q[3 * qi + 1];
    afrag[2] = (_Float16)q[3 * qi + 2];
    afrag[3] = (_Float16)1.0f;
  }
  __syncthreads();

  // B fragment address: quad0 lane holds B[k=0..7][n=col] for the tile;
  // lanes in quads 1..3 read the zero slot every iteration (step 0).
  const char* lds = (const char*)gsh;
  int off  = (quad == 0) ? col * 8 : NPTS * 8;
  int step = (quad == 0) ? 16 * 8 : 0;

  floatx4 macc = {3.0e38f, 3.0e38f, 3.0e38f, 3.0e38f};
#pragma unroll 4
  for (int t = 0; t < NTILE; t++) {
    uint2 w = *(const uint2*)(lds + off);
    off += step;
    union { int4 i; half8 h; } bu;
    bu.i = make_int4((int)w.x, (int)w.y, 0, 0);
    floatx4 r = __builtin_amdgcn_mfma_f32_16x16x32_f16(afrag, bu.h,
                                                       (floatx4){0.f, 0.f, 0.f, 0.f},
                                                       0, 0, 0);
    macc[0] = fminf(macc[0], r[0]);
    macc[1] = fminf(macc[1], r[1]);
    macc[2] = fminf(macc[2], r[2]);
    macc[3] = fminf(macc[3], r[3]);
  }

  // C/D layout: col=lane&15 (g), row=quad*4+reg (q). Min across the 16 cols.
#pragma unroll
  for (int mask = 1; mask < 16; mask <<= 1) {
#pragma unroll
    for (int r = 0; r < 4; r++)
      macc[r] = fminf(macc[r], __shfl_xor(macc[r], mask));
  }

  if (col == 0) {
    // rows q0 + quad*4 + (0..3): add exact fp32 qn, clamp, store as float4
    float4 outv;
#pragma unroll
    for (int r = 0; r < 4; r++) {
      int qi = q0 + quad * 4 + r;
      float qx = q[3 * qi + 0], qy = q[3 * qi + 1], qz = q[3 * qi + 2];
      float qn = qx * qx + qy * qy + qz * qz;
      ((float*)&outv)[r] = fmaxf(qn + macc[r], 0.0f);
    }
    *(float4*)(minsq + (size_t)bz * NPTS + q0 + quad * 4) = outv;
  }
}

// ---------------- Kernel B: sqrt + mean + exact top-k mean per row,
// then atomicAdd into out (out zeroed by nn_min, prior dispatch) ------------
__global__ __launch_bounds__(BT) void select_kernel(
    const float* __restrict__ minsq, float* __restrict__ out) {
  const int row = blockIdx.x;                // 0..15 = b*2+dir
  const float* src = minsq + (size_t)row * NPTS;
  const int tid = threadIdx.x;

  __shared__ float sf[4];
  __shared__ int   si[4];

  const int PER = NPTS / BT;  // 16 values per thread
  float d[PER];
  float sum_all = 0.0f;
#pragma unroll
  for (int j = 0; j < PER; j++) {
    float v = sqrtf(src[tid + BT * j]);
    d[j] = v;
    sum_all += v;
  }

  // block float sum of sum_all
  {
    float v = sum_all;
    for (int off = 32; off > 0; off >>= 1) v += __shfl_down(v, off);
    if ((tid & 63) == 0) sf[tid >> 6] = v;
    __syncthreads();
    sum_all = sf[0] + sf[1] + sf[2] + sf[3];
    __syncthreads();
  }

  // radix-select the TOPK-th largest value (exact, over float bit patterns)
  unsigned sel = 0u;
  for (int bit = 30; bit >= 0; --bit) {   // sign bit is 0 (nonneg)
    unsigned cand = sel | (1u << bit);
    int c = 0;
#pragma unroll
    for (int j = 0; j < PER; j++) c += (__float_as_uint(d[j]) >= cand) ? 1 : 0;
    for (int off = 32; off > 0; off >>= 1) c += __shfl_down(c, off);
    if ((tid & 63) == 0) si[tid >> 6] = c;
    __syncthreads();
    int total = si[0] + si[1] + si[2] + si[3];
    __syncthreads();
    if (total >= TOPK) sel = cand;
  }

  // sum of strictly-greater values + count
  int cgt = 0;
  float sgt = 0.0f;
#pragma unroll
  for (int j = 0; j < PER; j++) {
    if (__float_as_uint(d[j]) > sel) { cgt++; sgt += d[j]; }
  }
  {
    float v = sgt;
    for (int off = 32; off > 0; off >>= 1) v += __shfl_down(v, off);
    if ((tid & 63) == 0) sf[tid >> 6] = v;
    int c = cgt;
    for (int off = 32; off > 0; off >>= 1) c += __shfl_down(c, off);
    if ((tid & 63) == 0) si[tid >> 6] = c;
    __syncthreads();
    sgt = sf[0] + sf[1] + sf[2] + sf[3];
    cgt = si[0] + si[1] + si[2] + si[3];
  }

  if (tid == 0) {
    float kth = __uint_as_float(sel);
    float topk_sum = sgt + (float)(TOPK - cgt) * kth;  // tie-exact vs lax.top_k
    float rowval = sum_all / (float)NPTS + 3.0f * (topk_sum / (float)TOPK);
    atomicAdd(out, rowval * (1.0f / (float)BATCH));
  }
}

extern "C" void kernel_launch(void* const* d_in, const int* in_sizes, int n_in,
                              void* d_out, int out_size, void* d_ws, size_t ws_size,
                              hipStream_t stream) {
  const float* pred = (const float*)d_in[0];
  const float* gt   = (const float*)d_in[1];
  float* out = (float*)d_out;

  float* minsq = (float*)d_ws;   // [NROW][NPTS] = 256 KB

  dim3 gridA(NPTS / 64, NROW);   // (64,16) = 1024 blocks
  nn_min_kernel<<<gridA, BT, 0, stream>>>(pred, gt, minsq, out);
  select_kernel<<<NROW, BT, 0, stream>>>(minsq, out);
}